// Round 10
// baseline (155.533 us; speedup 1.0000x reference)
//
#include <hip/hip_runtime.h>
#include <hip/hip_bf16.h>
#include <math.h>

typedef short bf16x8 __attribute__((ext_vector_type(8)));      // 8 bf16 = 4 VGPRs
typedef short short4v __attribute__((ext_vector_type(4)));     // 4 bf16 = 2 VGPRs
typedef float f32x4 __attribute__((ext_vector_type(4)));
typedef float float4v __attribute__((ext_vector_type(4)));
typedef unsigned short ushort4v __attribute__((ext_vector_type(4))); // 8 bytes

// cheap elu: exp(x)-1 via hardware v_exp_f32 (error ~1e-7 abs, threshold 3.4e-4)
static __device__ __forceinline__ float eluf(float x) {
  float e = __expf(x) - 1.0f;
  return x > 0.f ? x : e;
}
static __device__ __forceinline__ unsigned short f2bf(float f) {
  __hip_bfloat16 h = __float2bfloat16(f);
  return *reinterpret_cast<unsigned short*>(&h);
}
static __device__ __forceinline__ unsigned short f2bf_rne(float f) {
  union { float f; unsigned u; } v; v.f = f;
  unsigned r = v.u + 0x7FFFu + ((v.u >> 16) & 1u);
  return (unsigned short)(r >> 16);
}

// ---------------- prologue 1: h = elu(A_flat @ W1^T), h[256] ----------------
__global__ void k_hidden(const float* __restrict__ A, const float* __restrict__ W1,
                         float* __restrict__ hout) {
  int j = blockIdx.x, t = threadIdx.x;
  const float* row = W1 + (size_t)j * 4096;
  float s = 0.f;
  for (int i = t; i < 4096; i += 256) s += A[i] * row[i];
  __shared__ float red[256];
  red[t] = s; __syncthreads();
  for (int off = 128; off > 0; off >>= 1) {
    if (t < off) red[t] += red[t + off];
    __syncthreads();
  }
  if (t == 0) {
    float x = red[0];
    hout[j] = x > 0.f ? x : expm1f(x);   // prologue: keep precise
  }
}

// -------- prologue 2 (fused): blocks 0-63 = D rownorm; blocks 64+ = T-transpose
__global__ void k_pre2(const float* __restrict__ hbuf, const float* __restrict__ W2,
                       unsigned short* __restrict__ Dout,
                       const float* __restrict__ T1, const float* __restrict__ T2,
                       unsigned short* __restrict__ T1T, unsigned short* __restrict__ T2T) {
  int t = threadIdx.x;
  if (blockIdx.x < 64) {
    int x = blockIdx.x;
    int lane = t & 63, w = t >> 6;
    __shared__ float hs[256];
    __shared__ float ad[64];
    hs[t] = hbuf[t];
    __syncthreads();
    for (int ei = 0; ei < 16; ++ei) {
      int e = w * 16 + ei;
      const float* row = W2 + (size_t)(x * 64 + e) * 256;
      float p = 0.f;
      for (int q = 0; q < 4; ++q) p += row[q * 64 + lane] * hs[q * 64 + lane];
      for (int off = 32; off > 0; off >>= 1) p += __shfl_down(p, off);
      if (lane == 0) ad[e] = fmaxf(p, 0.f);
    }
    __syncthreads();
    if (t < 64) {
      float v = ad[t];
      float rs = v;
      for (int off = 1; off < 64; off <<= 1) rs += __shfl_xor(rs, off);
      Dout[x * 64 + t] = f2bf_rne(v / fmaxf(rs, 1e-6f));
    }
  } else {
    int idx = (blockIdx.x - 64) * 256 + t;      // 0 .. 163839
    const float* src = (idx < 81920) ? T1 : T2;
    unsigned short* dst = (idx < 81920) ? T1T : T2T;
    int o = (idx < 81920) ? idx : idx - 81920;
    int g = o >> 14;
    int r = o & 16383;
    int h = r >> 7;      // out row = n index
    int f = r & 127;     // out col = k index
    dst[o] = f2bf_rne(src[g * 16384 + f * 128 + h]);
  }
}

// ---------------- main: per (g,b): out = elu(D @ elu(mu@T1) @ T2) ----------
// R4's proven no-spill schedule (vn prefetch + sched_barrier, t2b per-iter
// after GEMM1, aD inline in GEMM2) with s_h1 REMOVED via the in-register
// GEMM1->GEMM2 handoff (GEMM1 C-frag == 16x16x16 B-frag layout).
// Block = NB=4 b's for one g; 4 waves; wave w owns n-cols [32w,32w+32).
// LDS = 2x16KB bf16 mu double-buffer; h2 aliases bcur after B1.
// 2 barriers/iter. Persistent regs: tb only (32). No PIN (R9's spill lesson);
// (256,2) = the only bound that has never spilled.
__launch_bounds__(256, 2)
__global__ void k_main(const float* __restrict__ mu,
                       const unsigned short* __restrict__ Dm,
                       const unsigned short* __restrict__ T1T,
                       const unsigned short* __restrict__ T2T,
                       float* __restrict__ out) {
  __shared__ __align__(16) char smem[32768];

  const int g = blockIdx.y, b0 = blockIdx.x * 4;
  const int t = threadIdx.x;
  const int lane = t & 63, w = t >> 6;
  const int l15 = lane & 15, lk = lane >> 4;
  const int nb = w * 32;

  // ---- hoist T1 fragments only (32 regs persistent) ----
  const unsigned short* t1g = T1T + g * 16384;
  bf16x8 tb0[4], tb1[4];
  #pragma unroll
  for (int kc = 0; kc < 4; ++kc) {
    int k0 = kc * 32 + lk * 8;
    tb0[kc] = *(const bf16x8*)(const void*)(t1g + (nb + l15) * 128 + k0);
    tb1[kc] = *(const bf16x8*)(const void*)(t1g + (nb + 16 + l15) * 128 + k0);
  }

  // ---- prologue: stage mu for it=0 into buf0 (write-side cvt, swizzled) ----
  {
    const float4v* src = (const float4v*)(mu + (size_t)(g * 1024 + b0) * 8192);
    #pragma unroll
    for (int k = 0; k < 8; ++k) {
      int q = t + k * 256;
      float4v v = src[q];
      int row = q >> 5, col4 = (q & 31) * 4;
      ushort4v u;
      u[0] = f2bf(v[0]); u[1] = f2bf(v[1]); u[2] = f2bf(v[2]); u[3] = f2bf(v[3]);
      *(ushort4v*)(smem + ((row * 256 + col4 * 2) ^ ((row & 7) << 4))) = u;
    }
  }
  __syncthreads();

  #pragma unroll 1
  for (int it = 0; it < 4; ++it) {
    char* bcur = smem + ((it & 1) << 14);
    char* bnxt = smem + (((it + 1) & 1) << 14);
    const bool pre = (it < 3);

    // issue next-iter mu loads; pin issue point so hipcc can't sink them
    float4v vn[8];
    if (pre) {
      const float4v* srcn = (const float4v*)(mu + (size_t)(g * 1024 + b0 + it + 1) * 8192);
      #pragma unroll
      for (int k = 0; k < 8; ++k) vn[k] = srcn[t + k * 256];
      __builtin_amdgcn_sched_barrier(0);
    }

    // ---- GEMM1: h1 = mu @ T1 (M=e 64, N=h 128, K=f 128) ----
    f32x4 acc[4][2];
    #pragma unroll
    for (int m = 0; m < 4; ++m) { acc[m][0] = (f32x4){0,0,0,0}; acc[m][1] = (f32x4){0,0,0,0}; }
    #pragma unroll
    for (int kc = 0; kc < 4; ++kc) {
      int k0 = kc * 32 + lk * 8;
      #pragma unroll
      for (int m = 0; m < 4; ++m) {
        int row = m * 16 + l15;
        bf16x8 a = *(const bf16x8*)(bcur + ((row * 256 + k0 * 2) ^ ((row & 7) << 4)));
        acc[m][0] = __builtin_amdgcn_mfma_f32_16x16x32_bf16(a, tb0[kc], acc[m][0], 0, 0, 0);
        acc[m][1] = __builtin_amdgcn_mfma_f32_16x16x32_bf16(a, tb1[kc], acc[m][1], 0, 0, 0);
      }
    }

    // issue T2 fragment loads now (R4 position) — L2 latency hides under GEMM2
    const unsigned short* t2g = T2T + g * 16384;
    bf16x8 t2b0[4], t2b1[4];
    #pragma unroll
    for (int kc = 0; kc < 4; ++kc) {
      int k0 = kc * 32 + lk * 8;
      t2b0[kc] = *(const bf16x8*)(const void*)(t2g + (nb + l15) * 128 + k0);
      t2b1[kc] = *(const bf16x8*)(const void*)(t2g + (nb + 16 + l15) * 128 + k0);
    }

    // ---- elu + cvt -> bf16x4 B-frags for GEMM2 (registers only) ----
    short4v bfr[4][2];
    #pragma unroll
    for (int m = 0; m < 4; ++m)
      #pragma unroll
      for (int n = 0; n < 2; ++n) {
        short4v s;
        s[0] = (short)f2bf(eluf(acc[m][n][0]));
        s[1] = (short)f2bf(eluf(acc[m][n][1]));
        s[2] = (short)f2bf(eluf(acc[m][n][2]));
        s[3] = (short)f2bf(eluf(acc[m][n][3]));
        bfr[m][n] = s;
      }

    // ---- GEMM2: h2 = D @ h1 (M=x 64, N=h 128, K=e 64) via 16x16x16;
    //      aD loaded inline per use (8B, L1-hot — R4 pattern) ----
    f32x4 acc2[4][2];
    #pragma unroll
    for (int mp = 0; mp < 4; ++mp) { acc2[mp][0] = (f32x4){0,0,0,0}; acc2[mp][1] = (f32x4){0,0,0,0}; }
    #pragma unroll
    for (int kc = 0; kc < 4; ++kc)
      #pragma unroll
      for (int mp = 0; mp < 4; ++mp) {
        short4v aD = *(const short4v*)(const void*)(Dm + (mp * 16 + l15) * 64 + kc * 16 + lk * 4);
        acc2[mp][0] = __builtin_amdgcn_mfma_f32_16x16x16bf16_1k(aD, bfr[kc][0], acc2[mp][0], 0, 0, 0);
        acc2[mp][1] = __builtin_amdgcn_mfma_f32_16x16x16bf16_1k(aD, bfr[kc][1], acc2[mp][1], 0, 0, 0);
      }

    __syncthreads();   // B1: mu readers (it) + h2 readers (it-1) all done

    // ---- h2[x][h] scatter into bcur (b16 writes, swz on x) ----
    #pragma unroll
    for (int mp = 0; mp < 4; ++mp)
      #pragma unroll
      for (int n = 0; n < 2; ++n) {
        int hc = nb + n * 16 + l15;
        #pragma unroll
        for (int r = 0; r < 4; ++r) {
          int x = mp * 16 + lk * 4 + r;
          *(unsigned short*)(bcur + ((x * 256 + hc * 2) ^ ((x & 7) << 4))) = f2bf(acc2[mp][n][r]);
        }
      }
    // stage mu_{it+1} -> bnxt (vn waitcnt here; latency covered by G1+G2)
    if (pre) {
      #pragma unroll
      for (int k = 0; k < 8; ++k) {
        int q = t + k * 256;
        int row = q >> 5, col4 = (q & 31) * 4;
        ushort4v u;
        u[0] = f2bf(vn[k][0]); u[1] = f2bf(vn[k][1]);
        u[2] = f2bf(vn[k][2]); u[3] = f2bf(vn[k][3]);
        *(ushort4v*)(bnxt + ((row * 256 + col4 * 2) ^ ((row & 7) << 4))) = u;
      }
    }
    __syncthreads();   // B2: h2 + mu_next visible

    // ---- GEMM3: out = elu(h2 @ T2) (M=x 64, N=f 128, K=h 128) ----
    f32x4 acc3[4][2];
    #pragma unroll
    for (int m = 0; m < 4; ++m) { acc3[m][0] = (f32x4){0,0,0,0}; acc3[m][1] = (f32x4){0,0,0,0}; }
    #pragma unroll
    for (int kc = 0; kc < 4; ++kc) {
      int k0 = kc * 32 + lk * 8;
      #pragma unroll
      for (int m = 0; m < 4; ++m) {
        int row = m * 16 + l15;
        bf16x8 a = *(const bf16x8*)(bcur + ((row * 256 + k0 * 2) ^ ((row & 7) << 4)));
        acc3[m][0] = __builtin_amdgcn_mfma_f32_16x16x32_bf16(a, t2b0[kc], acc3[m][0], 0, 0, 0);
        acc3[m][1] = __builtin_amdgcn_mfma_f32_16x16x32_bf16(a, t2b1[kc], acc3[m][1], 0, 0, 0);
      }
    }
    float* ob = out + (size_t)(g * 1024 + b0 + it) * 8192;
    #pragma unroll
    for (int m = 0; m < 4; ++m)
      #pragma unroll
      for (int n = 0; n < 2; ++n) {
        int f = nb + n * 16 + l15;
        #pragma unroll
        for (int r = 0; r < 4; ++r) {
          int e = m * 16 + lk * 4 + r;
          ob[e * 128 + f] = eluf(acc3[m][n][r]);
        }
      }
  }
}

extern "C" void kernel_launch(void* const* d_in, const int* in_sizes, int n_in,
                              void* d_out, int out_size, void* d_ws, size_t ws_size,
                              hipStream_t stream) {
  const float* mu = (const float*)d_in[0];
  const float* A  = (const float*)d_in[1];
  const float* W1 = (const float*)d_in[2];
  const float* W2 = (const float*)d_in[3];
  const float* T1 = (const float*)d_in[4];
  const float* T2 = (const float*)d_in[5];
  float* out = (float*)d_out;

  char* ws = (char*)d_ws;
  float* hbuf          = (float*)ws;                     // 1 KB
  unsigned short* Dm   = (unsigned short*)(ws + 1024);   // 8 KB
  unsigned short* T1T  = (unsigned short*)(ws + 9216);   // 160 KB
  unsigned short* T2T  = (unsigned short*)(ws + 173056); // 160 KB

  hipLaunchKernelGGL(k_hidden, dim3(256), dim3(256), 0, stream, A, W1, hbuf);
  hipLaunchKernelGGL(k_pre2,   dim3(704), dim3(256), 0, stream, hbuf, W2, Dm, T1, T2, T1T, T2T);
  hipLaunchKernelGGL(k_main,   dim3(256, 5), dim3(256), 0, stream, mu, Dm, T1T, T2T, out);
}

// Round 11
// 113.178 us; speedup vs baseline: 1.3742x; 1.3742x over previous
//
#include <hip/hip_runtime.h>
#include <hip/hip_bf16.h>
#include <math.h>

typedef short bf16x8 __attribute__((ext_vector_type(8)));      // 8 bf16 = 4 VGPRs
typedef short short4v __attribute__((ext_vector_type(4)));     // 4 bf16 = 2 VGPRs
typedef float f32x4 __attribute__((ext_vector_type(4)));
typedef float float4v __attribute__((ext_vector_type(4)));
typedef unsigned short ushort4v __attribute__((ext_vector_type(4))); // 8 bytes

// cheap elu: exp(x)-1 via hardware v_exp_f32 (error ~1e-7 abs, threshold 3.4e-4)
static __device__ __forceinline__ float eluf(float x) {
  float e = __expf(x) - 1.0f;
  return x > 0.f ? x : e;
}
static __device__ __forceinline__ unsigned short f2bf(float f) {
  __hip_bfloat16 h = __float2bfloat16(f);
  return *reinterpret_cast<unsigned short*>(&h);
}
static __device__ __forceinline__ unsigned short f2bf_rne(float f) {
  union { float f; unsigned u; } v; v.f = f;
  unsigned r = v.u + 0x7FFFu + ((v.u >> 16) & 1u);
  return (unsigned short)(r >> 16);
}

// ---------------- prologue 1: h = elu(A_flat @ W1^T), h[256] ----------------
__global__ void k_hidden(const float* __restrict__ A, const float* __restrict__ W1,
                         float* __restrict__ hout) {
  int j = blockIdx.x, t = threadIdx.x;
  const float* row = W1 + (size_t)j * 4096;
  float s = 0.f;
  for (int i = t; i < 4096; i += 256) s += A[i] * row[i];
  __shared__ float red[256];
  red[t] = s; __syncthreads();
  for (int off = 128; off > 0; off >>= 1) {
    if (t < off) red[t] += red[t + off];
    __syncthreads();
  }
  if (t == 0) {
    float x = red[0];
    hout[j] = x > 0.f ? x : expm1f(x);   // prologue: keep precise
  }
}

// -------- prologue 2 (fused): blocks 0-63 = D rownorm; blocks 64+ = T-transpose
__global__ void k_pre2(const float* __restrict__ hbuf, const float* __restrict__ W2,
                       unsigned short* __restrict__ Dout,
                       const float* __restrict__ T1, const float* __restrict__ T2,
                       unsigned short* __restrict__ T1T, unsigned short* __restrict__ T2T) {
  int t = threadIdx.x;
  if (blockIdx.x < 64) {
    int x = blockIdx.x;
    int lane = t & 63, w = t >> 6;
    __shared__ float hs[256];
    __shared__ float ad[64];
    hs[t] = hbuf[t];
    __syncthreads();
    for (int ei = 0; ei < 16; ++ei) {
      int e = w * 16 + ei;
      const float* row = W2 + (size_t)(x * 64 + e) * 256;
      float p = 0.f;
      for (int q = 0; q < 4; ++q) p += row[q * 64 + lane] * hs[q * 64 + lane];
      for (int off = 32; off > 0; off >>= 1) p += __shfl_down(p, off);
      if (lane == 0) ad[e] = fmaxf(p, 0.f);
    }
    __syncthreads();
    if (t < 64) {
      float v = ad[t];
      float rs = v;
      for (int off = 1; off < 64; off <<= 1) rs += __shfl_xor(rs, off);
      Dout[x * 64 + t] = f2bf_rne(v / fmaxf(rs, 1e-6f));
    }
  } else {
    int idx = (blockIdx.x - 64) * 256 + t;      // 0 .. 163839
    const float* src = (idx < 81920) ? T1 : T2;
    unsigned short* dst = (idx < 81920) ? T1T : T2T;
    int o = (idx < 81920) ? idx : idx - 81920;
    int g = o >> 14;
    int r = o & 16383;
    int h = r >> 7;      // out row = n index
    int f = r & 127;     // out col = k index
    dst[o] = f2bf_rne(src[g * 16384 + f * 128 + h]);
  }
}

// ---------------- main: per (g,b): out = elu(D @ elu(mu@T1) @ T2) ----------
// 512 threads = 8 waves; wave w owns a 16-col n-slice [16w,16w+16) of
// h (GEMM1/2) and f (GEMM3). Halving the slice (vs 4-wave/32-col) halves
// the per-wave register footprint (acc 16, frags 16 each) -> ~100-128 total
// regs/wave -> 16 waves/CU (2 blocks) occupancy, the TLP every prior round
// lacked. Schedule = R4's proven no-spill pipeline: NB=4 tiles/block,
// vn prefetch at iter top (sched_barrier(0) pins issue), t2b issued after
// GEMM1, aD inline in GEMM2, in-register GEMM1->GEMM2 handoff (16x16x16
// B-frag identity), LDS = 2x16KB bf16 mu double-buffer, h2 aliases bcur,
// 2 barriers/iter.
__launch_bounds__(512, 2)
__global__ void k_main(const float* __restrict__ mu,
                       const unsigned short* __restrict__ Dm,
                       const unsigned short* __restrict__ T1T,
                       const unsigned short* __restrict__ T2T,
                       float* __restrict__ out) {
  __shared__ __align__(16) char smem[32768];

  const int g = blockIdx.y, b0 = blockIdx.x * 4;
  const int t = threadIdx.x;
  const int lane = t & 63, w = t >> 6;
  const int l15 = lane & 15, lk = lane >> 4;
  const int nb = w * 16;

  // ---- hoist T1 fragments (16 regs persistent) ----
  const unsigned short* t1g = T1T + g * 16384;
  bf16x8 tb[4];
  #pragma unroll
  for (int kc = 0; kc < 4; ++kc)
    tb[kc] = *(const bf16x8*)(const void*)(t1g + (nb + l15) * 128 + kc * 32 + lk * 8);

  // ---- prologue: stage mu for it=0 into buf0 (write-side cvt, swizzled) ----
  {
    const float4v* src = (const float4v*)(mu + (size_t)(g * 1024 + b0) * 8192);
    #pragma unroll
    for (int k = 0; k < 4; ++k) {
      int q = t + k * 512;
      float4v v = src[q];
      int row = q >> 5, col4 = (q & 31) * 4;
      ushort4v u;
      u[0] = f2bf(v[0]); u[1] = f2bf(v[1]); u[2] = f2bf(v[2]); u[3] = f2bf(v[3]);
      *(ushort4v*)(smem + ((row * 256 + col4 * 2) ^ ((row & 7) << 4))) = u;
    }
  }
  __syncthreads();

  #pragma unroll 1
  for (int it = 0; it < 4; ++it) {
    char* bcur = smem + ((it & 1) << 14);
    char* bnxt = smem + (((it + 1) & 1) << 14);
    const bool pre = (it < 3);

    // issue next-iter mu loads; pin issue point so hipcc can't sink them
    float4v vn[4];
    if (pre) {
      const float4v* srcn = (const float4v*)(mu + (size_t)(g * 1024 + b0 + it + 1) * 8192);
      #pragma unroll
      for (int k = 0; k < 4; ++k) vn[k] = srcn[t + k * 512];
      __builtin_amdgcn_sched_barrier(0);
    }

    // ---- GEMM1: h1 = mu @ T1 (M=e 64, N=h 16/wave, K=f 128) ----
    f32x4 acc[4];
    #pragma unroll
    for (int m = 0; m < 4; ++m) acc[m] = (f32x4){0, 0, 0, 0};
    #pragma unroll
    for (int kc = 0; kc < 4; ++kc) {
      int k0 = kc * 32 + lk * 8;
      #pragma unroll
      for (int m = 0; m < 4; ++m) {
        int row = m * 16 + l15;
        bf16x8 a = *(const bf16x8*)(bcur + ((row * 256 + k0 * 2) ^ ((row & 7) << 4)));
        acc[m] = __builtin_amdgcn_mfma_f32_16x16x32_bf16(a, tb[kc], acc[m], 0, 0, 0);
      }
    }

    // issue T2 fragment loads now (R4 position) — L2 latency hides under GEMM2
    const unsigned short* t2g = T2T + g * 16384;
    bf16x8 t2b[4];
    #pragma unroll
    for (int kc = 0; kc < 4; ++kc)
      t2b[kc] = *(const bf16x8*)(const void*)(t2g + (nb + l15) * 128 + kc * 32 + lk * 8);

    // ---- elu + cvt -> bf16x4 B-frags for GEMM2 (registers only) ----
    short4v bfr[4];
    #pragma unroll
    for (int m = 0; m < 4; ++m) {
      short4v s;
      s[0] = (short)f2bf(eluf(acc[m][0]));
      s[1] = (short)f2bf(eluf(acc[m][1]));
      s[2] = (short)f2bf(eluf(acc[m][2]));
      s[3] = (short)f2bf(eluf(acc[m][3]));
      bfr[m] = s;
    }

    // ---- GEMM2: h2 = D @ h1 (M=x 64, N=h 16/wave, K=e 64) via 16x16x16;
    //      aD loaded inline per use (8B, L1-hot) ----
    f32x4 acc2[4];
    #pragma unroll
    for (int mp = 0; mp < 4; ++mp) acc2[mp] = (f32x4){0, 0, 0, 0};
    #pragma unroll
    for (int kc = 0; kc < 4; ++kc)
      #pragma unroll
      for (int mp = 0; mp < 4; ++mp) {
        short4v aD = *(const short4v*)(const void*)(Dm + (mp * 16 + l15) * 64 + kc * 16 + lk * 4);
        acc2[mp] = __builtin_amdgcn_mfma_f32_16x16x16bf16_1k(aD, bfr[kc], acc2[mp], 0, 0, 0);
      }

    __syncthreads();   // B1: mu readers (it) + h2 readers (it-1) all done

    // ---- h2[x][h] scatter into bcur (b16 writes, swz on x) ----
    #pragma unroll
    for (int mp = 0; mp < 4; ++mp) {
      int hc = nb + l15;
      #pragma unroll
      for (int r = 0; r < 4; ++r) {
        int x = mp * 16 + lk * 4 + r;
        *(unsigned short*)(bcur + ((x * 256 + hc * 2) ^ ((x & 7) << 4))) = f2bf(acc2[mp][r]);
      }
    }
    // stage mu_{it+1} -> bnxt (vn waitcnt here; latency covered by G1+G2)
    if (pre) {
      #pragma unroll
      for (int k = 0; k < 4; ++k) {
        int q = t + k * 512;
        int row = q >> 5, col4 = (q & 31) * 4;
        ushort4v u;
        u[0] = f2bf(vn[k][0]); u[1] = f2bf(vn[k][1]);
        u[2] = f2bf(vn[k][2]); u[3] = f2bf(vn[k][3]);
        *(ushort4v*)(bnxt + ((row * 256 + col4 * 2) ^ ((row & 7) << 4))) = u;
      }
    }
    __syncthreads();   // B2: h2 + mu_next visible

    // ---- GEMM3: out = elu(h2 @ T2) (M=x 64, N=f 16/wave, K=h 128) ----
    f32x4 acc3[4];
    #pragma unroll
    for (int m = 0; m < 4; ++m) acc3[m] = (f32x4){0, 0, 0, 0};
    #pragma unroll
    for (int kc = 0; kc < 4; ++kc) {
      int k0 = kc * 32 + lk * 8;
      #pragma unroll
      for (int m = 0; m < 4; ++m) {
        int row = m * 16 + l15;
        bf16x8 a = *(const bf16x8*)(bcur + ((row * 256 + k0 * 2) ^ ((row & 7) << 4)));
        acc3[m] = __builtin_amdgcn_mfma_f32_16x16x32_bf16(a, t2b[kc], acc3[m], 0, 0, 0);
      }
    }
    float* ob = out + (size_t)(g * 1024 + b0 + it) * 8192;
    #pragma unroll
    for (int m = 0; m < 4; ++m) {
      int f = nb + l15;
      #pragma unroll
      for (int r = 0; r < 4; ++r) {
        int e = m * 16 + lk * 4 + r;
        ob[e * 128 + f] = eluf(acc3[m][r]);
      }
    }
  }
}

extern "C" void kernel_launch(void* const* d_in, const int* in_sizes, int n_in,
                              void* d_out, int out_size, void* d_ws, size_t ws_size,
                              hipStream_t stream) {
  const float* mu = (const float*)d_in[0];
  const float* A  = (const float*)d_in[1];
  const float* W1 = (const float*)d_in[2];
  const float* W2 = (const float*)d_in[3];
  const float* T1 = (const float*)d_in[4];
  const float* T2 = (const float*)d_in[5];
  float* out = (float*)d_out;

  char* ws = (char*)d_ws;
  float* hbuf          = (float*)ws;                     // 1 KB
  unsigned short* Dm   = (unsigned short*)(ws + 1024);   // 8 KB
  unsigned short* T1T  = (unsigned short*)(ws + 9216);   // 160 KB
  unsigned short* T2T  = (unsigned short*)(ws + 173056); // 160 KB

  hipLaunchKernelGGL(k_hidden, dim3(256), dim3(256), 0, stream, A, W1, hbuf);
  hipLaunchKernelGGL(k_pre2,   dim3(704), dim3(256), 0, stream, hbuf, W2, Dm, T1, T2, T1T, T2T);
  hipLaunchKernelGGL(k_main,   dim3(256, 5), dim3(512), 0, stream, mu, Dm, T1T, T2T, out);
}

// Round 12
// 112.212 us; speedup vs baseline: 1.3861x; 1.0086x over previous
//
#include <hip/hip_runtime.h>
#include <hip/hip_bf16.h>
#include <math.h>

typedef short bf16x8 __attribute__((ext_vector_type(8)));      // 8 bf16 = 4 VGPRs
typedef short short4v __attribute__((ext_vector_type(4)));     // 4 bf16 = 2 VGPRs
typedef float f32x4 __attribute__((ext_vector_type(4)));
typedef float float4v __attribute__((ext_vector_type(4)));
typedef unsigned short ushort4v __attribute__((ext_vector_type(4))); // 8 bytes

// cheap elu: exp(x)-1 via hardware v_exp_f32 (error ~1e-7 abs, threshold 3.4e-4)
static __device__ __forceinline__ float eluf(float x) {
  float e = __expf(x) - 1.0f;
  return x > 0.f ? x : e;
}
static __device__ __forceinline__ unsigned short f2bf(float f) {
  __hip_bfloat16 h = __float2bfloat16(f);
  return *reinterpret_cast<unsigned short*>(&h);
}
static __device__ __forceinline__ unsigned short f2bf_rne(float f) {
  union { float f; unsigned u; } v; v.f = f;
  unsigned r = v.u + 0x7FFFu + ((v.u >> 16) & 1u);
  return (unsigned short)(r >> 16);
}

// ---------------- prologue 1: h = elu(A_flat @ W1^T), h[256] ----------------
__global__ void k_hidden(const float* __restrict__ A, const float* __restrict__ W1,
                         float* __restrict__ hout) {
  int j = blockIdx.x, t = threadIdx.x;
  const float* row = W1 + (size_t)j * 4096;
  float s = 0.f;
  for (int i = t; i < 4096; i += 256) s += A[i] * row[i];
  __shared__ float red[256];
  red[t] = s; __syncthreads();
  for (int off = 128; off > 0; off >>= 1) {
    if (t < off) red[t] += red[t + off];
    __syncthreads();
  }
  if (t == 0) {
    float x = red[0];
    hout[j] = x > 0.f ? x : expm1f(x);   // prologue: keep precise
  }
}

// -------- prologue 2 (fused): blocks 0-63 = D rownorm; blocks 64+ = T-transpose
__global__ void k_pre2(const float* __restrict__ hbuf, const float* __restrict__ W2,
                       unsigned short* __restrict__ Dout,
                       const float* __restrict__ T1, const float* __restrict__ T2,
                       unsigned short* __restrict__ T1T, unsigned short* __restrict__ T2T) {
  int t = threadIdx.x;
  if (blockIdx.x < 64) {
    int x = blockIdx.x;
    int lane = t & 63, w = t >> 6;
    __shared__ float hs[256];
    __shared__ float ad[64];
    hs[t] = hbuf[t];
    __syncthreads();
    for (int ei = 0; ei < 16; ++ei) {
      int e = w * 16 + ei;
      const float* row = W2 + (size_t)(x * 64 + e) * 256;
      float p = 0.f;
      for (int q = 0; q < 4; ++q) p += row[q * 64 + lane] * hs[q * 64 + lane];
      for (int off = 32; off > 0; off >>= 1) p += __shfl_down(p, off);
      if (lane == 0) ad[e] = fmaxf(p, 0.f);
    }
    __syncthreads();
    if (t < 64) {
      float v = ad[t];
      float rs = v;
      for (int off = 1; off < 64; off <<= 1) rs += __shfl_xor(rs, off);
      Dout[x * 64 + t] = f2bf_rne(v / fmaxf(rs, 1e-6f));
    }
  } else {
    int idx = (blockIdx.x - 64) * 256 + t;      // 0 .. 163839
    const float* src = (idx < 81920) ? T1 : T2;
    unsigned short* dst = (idx < 81920) ? T1T : T2T;
    int o = (idx < 81920) ? idx : idx - 81920;
    int g = o >> 14;
    int r = o & 16383;
    int h = r >> 7;      // out row = n index
    int f = r & 127;     // out col = k index
    dst[o] = f2bf_rne(src[g * 16384 + f * 128 + h]);
  }
}

// ---------------- main: per (g,b): out = elu(D @ elu(mu@T1) @ T2) ----------
// 512 threads = 8 waves; wave w owns 16-col n-slice [16w,16w+16).
// ONE barrier per iteration: mu double-buffered AND h2 double-buffered
// (LDS 64KB = mu0,mu1,h2_0,h2_1; 2 blocks/CU = the VGPR cap anyway).
// Orderings per iter all satisfied by the single barrier after
// {scatter h2cur, stage mu_next}: (a) h2 writes -> h2 reads (GEMM3 after
// barrier); (b) stage -> next GEMM1 (after barrier); buffer parity keeps
// concurrent phases on disjoint buffers (each wave: barrier(it) -> GEMM3(it)
// -> GEMM1(it+1) -> barrier(it+1), so no wave gets 2 barriers ahead).
// KEY: vn's vmcnt wait happens AT THE STAGE WRITE, before the barrier, so
// __syncthreads()' implicit vmcnt(0) drain is free — the R4-R11 stall
// (prefetch drained at a barrier before use) is gone. In-register
// GEMM1->GEMM2 handoff (16x16x16 B-frag identity); t2b issued post-GEMM1;
// aD inline (L1-hot); (512,2) — never spilled.
__launch_bounds__(512, 2)
__global__ void k_main(const float* __restrict__ mu,
                       const unsigned short* __restrict__ Dm,
                       const unsigned short* __restrict__ T1T,
                       const unsigned short* __restrict__ T2T,
                       float* __restrict__ out) {
  __shared__ __align__(16) char smem[65536];   // mu0,mu1 @0,16K; h2_0,h2_1 @32K,48K

  const int g = blockIdx.y, b0 = blockIdx.x * 4;
  const int t = threadIdx.x;
  const int lane = t & 63, w = t >> 6;
  const int l15 = lane & 15, lk = lane >> 4;
  const int nb = w * 16;

  // ---- hoist T1 fragments (16 regs persistent) ----
  const unsigned short* t1g = T1T + g * 16384;
  bf16x8 tb[4];
  #pragma unroll
  for (int kc = 0; kc < 4; ++kc)
    tb[kc] = *(const bf16x8*)(const void*)(t1g + (nb + l15) * 128 + kc * 32 + lk * 8);

  // ---- prologue: stage mu for it=0 into mu0 (write-side cvt, swizzled) ----
  {
    const float4v* src = (const float4v*)(mu + (size_t)(g * 1024 + b0) * 8192);
    #pragma unroll
    for (int k = 0; k < 4; ++k) {
      int q = t + k * 512;
      float4v v = src[q];
      int row = q >> 5, col4 = (q & 31) * 4;
      ushort4v u;
      u[0] = f2bf(v[0]); u[1] = f2bf(v[1]); u[2] = f2bf(v[2]); u[3] = f2bf(v[3]);
      *(ushort4v*)(smem + ((row * 256 + col4 * 2) ^ ((row & 7) << 4))) = u;
    }
  }
  __syncthreads();

  #pragma unroll 1
  for (int it = 0; it < 4; ++it) {
    char* bcur = smem + ((it & 1) << 14);
    char* bnxt = smem + (((it + 1) & 1) << 14);
    char* h2c  = smem + 32768 + ((it & 1) << 14);
    const bool pre = (it < 3);

    // issue next-iter mu loads; pin issue point so hipcc can't sink them
    float4v vn[4];
    if (pre) {
      const float4v* srcn = (const float4v*)(mu + (size_t)(g * 1024 + b0 + it + 1) * 8192);
      #pragma unroll
      for (int k = 0; k < 4; ++k) vn[k] = srcn[t + k * 512];
      __builtin_amdgcn_sched_barrier(0);
    }

    // ---- GEMM1: h1 = mu @ T1 (M=e 64, N=h 16/wave, K=f 128) ----
    f32x4 acc[4];
    #pragma unroll
    for (int m = 0; m < 4; ++m) acc[m] = (f32x4){0, 0, 0, 0};
    #pragma unroll
    for (int kc = 0; kc < 4; ++kc) {
      int k0 = kc * 32 + lk * 8;
      #pragma unroll
      for (int m = 0; m < 4; ++m) {
        int row = m * 16 + l15;
        bf16x8 a = *(const bf16x8*)(bcur + ((row * 256 + k0 * 2) ^ ((row & 7) << 4)));
        acc[m] = __builtin_amdgcn_mfma_f32_16x16x32_bf16(a, tb[kc], acc[m], 0, 0, 0);
      }
    }

    // issue T2 fragment loads now — L2 latency hides under cvt+GEMM2
    const unsigned short* t2g = T2T + g * 16384;
    bf16x8 t2b[4];
    #pragma unroll
    for (int kc = 0; kc < 4; ++kc)
      t2b[kc] = *(const bf16x8*)(const void*)(t2g + (nb + l15) * 128 + kc * 32 + lk * 8);

    // ---- elu + cvt -> bf16x4 B-frags for GEMM2 (registers only) ----
    short4v bfr[4];
    #pragma unroll
    for (int m = 0; m < 4; ++m) {
      short4v s;
      s[0] = (short)f2bf(eluf(acc[m][0]));
      s[1] = (short)f2bf(eluf(acc[m][1]));
      s[2] = (short)f2bf(eluf(acc[m][2]));
      s[3] = (short)f2bf(eluf(acc[m][3]));
      bfr[m] = s;
    }

    // ---- GEMM2: h2 = D @ h1 (M=x 64, N=h 16/wave, K=e 64) via 16x16x16;
    //      aD loaded inline per use (8B, L1-hot) ----
    f32x4 acc2[4];
    #pragma unroll
    for (int mp = 0; mp < 4; ++mp) acc2[mp] = (f32x4){0, 0, 0, 0};
    #pragma unroll
    for (int kc = 0; kc < 4; ++kc)
      #pragma unroll
      for (int mp = 0; mp < 4; ++mp) {
        short4v aD = *(const short4v*)(const void*)(Dm + (mp * 16 + l15) * 64 + kc * 16 + lk * 4);
        acc2[mp] = __builtin_amdgcn_mfma_f32_16x16x16bf16_1k(aD, bfr[kc], acc2[mp], 0, 0, 0);
      }

    // ---- h2[x][h] scatter into h2c (b16 writes, swz on x) ----
    #pragma unroll
    for (int mp = 0; mp < 4; ++mp) {
      int hc = nb + l15;
      #pragma unroll
      for (int r = 0; r < 4; ++r) {
        int x = mp * 16 + lk * 4 + r;
        *(unsigned short*)(h2c + ((x * 256 + hc * 2) ^ ((x & 7) << 4))) = f2bf(acc2[mp][r]);
      }
    }
    // stage mu_{it+1} -> bnxt; the vmcnt wait for vn lands HERE (pre-barrier),
    // covered by GEMM1+t2b+cvt+GEMM2 — so the barrier drain below is free.
    if (pre) {
      #pragma unroll
      for (int k = 0; k < 4; ++k) {
        int q = t + k * 512;
        int row = q >> 5, col4 = (q & 31) * 4;
        ushort4v u;
        u[0] = f2bf(vn[k][0]); u[1] = f2bf(vn[k][1]);
        u[2] = f2bf(vn[k][2]); u[3] = f2bf(vn[k][3]);
        *(ushort4v*)(bnxt + ((row * 256 + col4 * 2) ^ ((row & 7) << 4))) = u;
      }
    }
    __syncthreads();   // the ONLY barrier: h2c + mu_next visible; nothing pending

    // ---- GEMM3: out = elu(h2 @ T2) (M=x 64, N=f 16/wave, K=h 128) ----
    f32x4 acc3[4];
    #pragma unroll
    for (int m = 0; m < 4; ++m) acc3[m] = (f32x4){0, 0, 0, 0};
    #pragma unroll
    for (int kc = 0; kc < 4; ++kc) {
      int k0 = kc * 32 + lk * 8;
      #pragma unroll
      for (int m = 0; m < 4; ++m) {
        int row = m * 16 + l15;
        bf16x8 a = *(const bf16x8*)(h2c + ((row * 256 + k0 * 2) ^ ((row & 7) << 4)));
        acc3[m] = __builtin_amdgcn_mfma_f32_16x16x32_bf16(a, t2b[kc], acc3[m], 0, 0, 0);
      }
    }
    float* ob = out + (size_t)(g * 1024 + b0 + it) * 8192;
    #pragma unroll
    for (int m = 0; m < 4; ++m) {
      int f = nb + l15;
      #pragma unroll
      for (int r = 0; r < 4; ++r) {
        int e = m * 16 + lk * 4 + r;
        ob[e * 128 + f] = eluf(acc3[m][r]);
      }
    }
  }
}

extern "C" void kernel_launch(void* const* d_in, const int* in_sizes, int n_in,
                              void* d_out, int out_size, void* d_ws, size_t ws_size,
                              hipStream_t stream) {
  const float* mu = (const float*)d_in[0];
  const float* A  = (const float*)d_in[1];
  const float* W1 = (const float*)d_in[2];
  const float* W2 = (const float*)d_in[3];
  const float* T1 = (const float*)d_in[4];
  const float* T2 = (const float*)d_in[5];
  float* out = (float*)d_out;

  char* ws = (char*)d_ws;
  float* hbuf          = (float*)ws;                     // 1 KB
  unsigned short* Dm   = (unsigned short*)(ws + 1024);   // 8 KB
  unsigned short* T1T  = (unsigned short*)(ws + 9216);   // 160 KB
  unsigned short* T2T  = (unsigned short*)(ws + 173056); // 160 KB

  hipLaunchKernelGGL(k_hidden, dim3(256), dim3(256), 0, stream, A, W1, hbuf);
  hipLaunchKernelGGL(k_pre2,   dim3(704), dim3(256), 0, stream, hbuf, W2, Dm, T1, T2, T1T, T2T);
  hipLaunchKernelGGL(k_main,   dim3(256, 5), dim3(512), 0, stream, mu, Dm, T1T, T2T, out);
}